// Round 4
// baseline (180.680 us; speedup 1.0000x reference)
//
#include <hip/hip_runtime.h>
#include <stdint.h>

#define Bn 256
#define Tn 50
#define Mn 20
#define En 128
#define G3 384
#define MT 64
#define LDA 132

typedef float f32x4 __attribute__((ext_vector_type(4)));

__device__ __forceinline__ float sigmoidf(float x) {
    return 1.0f / (1.0f + __expf(-x));
}
__device__ __forceinline__ float tanh_safe(float a) {
    float ax = fabsf(a);
    float e2 = __expf(-2.0f * ax);
    return copysignf((1.0f - e2) / (1.0f + e2), a);
}

// Opaque-definition global load: the value is DEFINED by volatile asm, so
// LLVM can neither rematerialize the load in-loop nor sink it — the only
// options are VGPR-residency or scratch spill, and under budget it keeps it.
__device__ __forceinline__ f32x4 gload4(const float* p) {
    f32x4 r;
    asm volatile("global_load_dwordx4 %0, %1, off"
                 : "=v"(r) : "v"(p) : "memory");
    return r;
}

// DPP quad_perm butterfly adds over the 4-lane quad (q = tid&3).
__device__ __forceinline__ float quad_reduce_add(float x) {
    int t1 = __builtin_amdgcn_update_dpp(0, __float_as_int(x),
                                         0xB1 /*[1,0,3,2]*/, 0xF, 0xF, true);
    x += __int_as_float(t1);
    int t2 = __builtin_amdgcn_update_dpp(0, __float_as_int(x),
                                         0x4E /*[2,3,0,1]*/, 0xF, 0xF, true);
    x += __int_as_float(t2);
    return x;   // all 4 lanes of the quad hold the total
}

// ---------------------------------------------------------------------------
// Kernel 1: basket-mean gather -> ub [B*T][128]  (stored in d_out region)
// ---------------------------------------------------------------------------
__global__ __launch_bounds__(256) void gather_kernel(
    const int*   __restrict__ item_ids,
    const int*   __restrict__ basket_sizes,
    const float* __restrict__ emb,
    float* __restrict__ ub)
{
    const int bt   = blockIdx.x * 8 + (threadIdx.x >> 5);
    const int lane = threadIdx.x & 31;
    const int* ids = item_ids + (size_t)bt * Mn;
    float ax = 0.f, ay = 0.f, az = 0.f, aw = 0.f;
    #pragma unroll
    for (int m = 0; m < Mn; ++m) {
        const float4 v = *(const float4*)(emb + (size_t)ids[m] * En + lane * 4);
        ax += v.x; ay += v.y; az += v.z; aw += v.w;
    }
    const float inv = 1.0f / (float)basket_sizes[bt];
    *(float4*)(ub + (size_t)bt * En + lane * 4) =
        make_float4(ax * inv, ay * inv, az * inv, aw * inv);
}

// ---------------------------------------------------------------------------
// Kernel 2: xg = ub @ W_ih^T + b_ih.  1200 blocks (200 M x 6 N); 4x4 tile.
// ---------------------------------------------------------------------------
__global__ __launch_bounds__(256, 2) void gemm_kernel(
    const float* __restrict__ ub,
    const float* __restrict__ W_ih,
    const float* __restrict__ b_ih,
    float* __restrict__ xg)
{
    __shared__ float A[MT][LDA];
    __shared__ float Bt[64][LDA];

    const int tid  = threadIdx.x;
    const int mt   = blockIdx.x / 6;
    const int nc   = blockIdx.x % 6;
    const int row0 = mt * MT;
    const int col0 = nc * 64;

    {
        const int r = tid >> 2, seg = tid & 3;
        const float4* srcA = (const float4*)(ub + (size_t)(row0 + r) * En + seg * 32);
        const float4* srcB = (const float4*)(W_ih + (size_t)(col0 + r) * En + seg * 32);
        float4* dstA = (float4*)&A[r][seg * 32];
        float4* dstB = (float4*)&Bt[r][seg * 32];
        #pragma unroll
        for (int c = 0; c < 8; ++c) { dstA[c] = srcA[c]; dstB[c] = srcB[c]; }
    }
    __syncthreads();

    const int tx = tid & 15;
    const int ty = tid >> 4;

    float acc[4][4];
    #pragma unroll
    for (int i = 0; i < 4; ++i)
        #pragma unroll
        for (int u = 0; u < 4; ++u) acc[i][u] = 0.0f;

    #pragma unroll 4
    for (int k4 = 0; k4 < 32; ++k4) {
        const float4 av[4] = {
            *(const float4*)&A[ty +  0][k4*4], *(const float4*)&A[ty + 16][k4*4],
            *(const float4*)&A[ty + 32][k4*4], *(const float4*)&A[ty + 48][k4*4]};
        const float4 bv[4] = {
            *(const float4*)&Bt[tx +  0][k4*4], *(const float4*)&Bt[tx + 16][k4*4],
            *(const float4*)&Bt[tx + 32][k4*4], *(const float4*)&Bt[tx + 48][k4*4]};
        #pragma unroll
        for (int i = 0; i < 4; ++i)
            #pragma unroll
            for (int u = 0; u < 4; ++u) {
                acc[i][u] = fmaf(av[i].x, bv[u].x, acc[i][u]);
                acc[i][u] = fmaf(av[i].y, bv[u].y, acc[i][u]);
                acc[i][u] = fmaf(av[i].z, bv[u].z, acc[i][u]);
                acc[i][u] = fmaf(av[i].w, bv[u].w, acc[i][u]);
            }
    }

    float bias[4];
    #pragma unroll
    for (int u = 0; u < 4; ++u) bias[u] = b_ih[col0 + tx + 16*u];
    #pragma unroll
    for (int i = 0; i < 4; ++i) {
        const size_t rowoff = (size_t)(row0 + ty + 16*i) * G3;
        #pragma unroll
        for (int u = 0; u < 4; ++u)
            xg[rowoff + col0 + tx + 16*u] = acc[i][u] + bias[u];
    }
}

// ---------------------------------------------------------------------------
// Kernel 3: sequential GRU. 256 blocks x 512 threads (8 waves, 2/SIMD).
// Thread (j in [0,128), q in [0,4)) owns gate rows {j,128+j,256+j} of W_hh,
// cols [q*32,q*32+32) = 96 weight floats.
//
// ROUND-4 FIX: VGPR_Count=72 proved rounds 0-3 all RE-FETCHED the 196KB
// weight set from L2 every step (~1500 cyc of the 2093 cyc/step).  A value
// pin (asm "+v") was a silent no-op.  Now the weights are DEFINED by
// volatile inline-asm global_load_dwordx4: LLVM cannot remat or sink a
// volatile asm, so the values must stay in VGPRs (96 + ~50 working < 256
// budget at launch_bounds(512,2)).  Success signature: VGPR_Count >= ~150.
// ---------------------------------------------------------------------------
__global__ __launch_bounds__(512, 2) void gru_kernel(
    const int*   __restrict__ lengths,
    const float* __restrict__ W_hh,
    const float* __restrict__ b_hh,
    const float* __restrict__ h0,
    const float* __restrict__ xg,
    float* __restrict__ out_dyn,
    float* __restrict__ out_h)
{
    __shared__ float hs[2][En];

    const int tid = threadIdx.x;
    const int b   = blockIdx.x;
    const int j   = tid >> 2;        // [0,128)
    const int q   = tid & 3;         // [0,4) — the DPP quad

    // Weight fragments via opaque asm loads, rotated by q at load time so
    // compute indices are compile-time constants.
    f32x4 w0[8], w1[8], w2[8];
    {
        const f32x4* p0 = (const f32x4*)(W_hh + (size_t)(0*En + j) * En + q * 32);
        const f32x4* p1 = (const f32x4*)(W_hh + (size_t)(1*En + j) * En + q * 32);
        const f32x4* p2 = (const f32x4*)(W_hh + (size_t)(2*En + j) * En + q * 32);
        #pragma unroll
        for (int c = 0; c < 8; ++c) {
            const int cc = (c + 2*q) & 7;
            w0[c] = gload4((const float*)(p0 + cc));
            w1[c] = gload4((const float*)(p1 + cc));
            w2[c] = gload4((const float*)(p2 + cc));
        }
    }
    // Drain the asm loads (compiler doesn't track asm-def data readiness),
    // and fence scheduling per rule #18.
    asm volatile("s_waitcnt vmcnt(0)" ::: "memory");
    __builtin_amdgcn_sched_barrier(0);

    const int len = lengths[b];
    const float* xgb = xg + (size_t)b * Tn * G3;
    float* outb = out_dyn + (size_t)b * Tn * En;

    const float br = b_hh[j], bz = b_hh[En + j], bn = b_hh[2*En + j];
    float hprev = h0[(size_t)b * En + j];
    if (q == 0) hs[0][j] = hprev;

    // xg software pipeline, depth 2: x0 = step t, x1 = step t+1.
    float x0r = xgb[j], x0z = xgb[En + j], x0n = xgb[2*En + j];
    const int t1 = (1 < len) ? 1 : 0;
    float x1r = xgb[t1*G3 + j], x1z = xgb[t1*G3 + En + j], x1n = xgb[t1*G3 + 2*En + j];
    __syncthreads();   // one-time full drain: hs[0] + x0/x1 resident

    int cur = 0;
    for (int t = 0; t < len; ++t) {
        // issue prefetch for t+2 at the top: ~2 steps of latency-hiding window
        const int tn = (t + 2 < len) ? t + 2 : len - 1;
        const float fr  = xgb[tn*G3 + j];
        const float fz  = xgb[tn*G3 + En + j];
        const float fnn = xgb[tn*G3 + 2*En + j];

        // partial dots over this thread's 32-col K-slice (bank-conflict-free
        // via the rotated walk)
        const f32x4* h4 = ((const f32x4*)hs[cur]) + q * 8;
        float a0 = 0.f, a1 = 0.f, a2 = 0.f;
        #pragma unroll
        for (int c = 0; c < 8; ++c) {
            const f32x4 hv = h4[(c + 2*q) & 7];
            a0 = fmaf(w0[c].x, hv.x, a0); a0 = fmaf(w0[c].y, hv.y, a0);
            a0 = fmaf(w0[c].z, hv.z, a0); a0 = fmaf(w0[c].w, hv.w, a0);
            a1 = fmaf(w1[c].x, hv.x, a1); a1 = fmaf(w1[c].y, hv.y, a1);
            a1 = fmaf(w1[c].z, hv.z, a1); a1 = fmaf(w1[c].w, hv.w, a1);
            a2 = fmaf(w2[c].x, hv.x, a2); a2 = fmaf(w2[c].y, hv.y, a2);
            a2 = fmaf(w2[c].z, hv.z, a2); a2 = fmaf(w2[c].w, hv.w, a2);
        }

        // in-quad butterfly reduce over q — DPP, pure VALU
        a0 = quad_reduce_add(a0);
        a1 = quad_reduce_add(a1);
        a2 = quad_reduce_add(a2);

        // gates — computed redundantly by all 4 q-lanes
        const float r = sigmoidf(x0r + br + a0);
        const float z = sigmoidf(x0z + bz + a1);
        const float n = tanh_safe(x0n + r * (bn + a2));
        const float hnew = (1.0f - z) * n + z * hprev;

        if (q == 0) {
            hs[cur ^ 1][j] = hnew;      // write the OTHER buffer
            outb[t*En + j] = hnew;      // fire-and-forget: never drained in-loop
        }
        // Raw barrier: drain LDS only (own reads + the hnew write), leave
        // global loads/stores in flight across the barrier.
        asm volatile("s_waitcnt lgkmcnt(0)" ::: "memory");
        __builtin_amdgcn_s_barrier();
        __builtin_amdgcn_sched_barrier(0);

        hprev = hnew;
        x0r = x1r; x0z = x1z; x0n = x1n;
        x1r = fr;  x1z = fz;  x1n = fnn;
        cur ^= 1;
    }

    if (q == 0) {
        for (int t = len; t < Tn; ++t) outb[t*En + j] = 0.0f;
        out_h[(size_t)b * En + j] = hprev;
    }
}

extern "C" void kernel_launch(void* const* d_in, const int* in_sizes, int n_in,
                              void* d_out, int out_size, void* d_ws, size_t ws_size,
                              hipStream_t stream) {
    const int*   item_ids     = (const int*)d_in[0];
    const int*   basket_sizes = (const int*)d_in[1];
    const int*   lengths      = (const int*)d_in[2];
    const float* emb          = (const float*)d_in[3];
    const float* W_ih         = (const float*)d_in[4];
    const float* W_hh         = (const float*)d_in[5];
    const float* b_ih         = (const float*)d_in[6];
    const float* b_hh         = (const float*)d_in[7];
    const float* h0           = (const float*)d_in[8];
    float* out = (float*)d_out;
    float* xg  = (float*)d_ws;   // 19.7 MB
    float* ub  = out;            // reuse out_dyn region; overwritten by gru later

    gather_kernel<<<(Bn * Tn) / 8, 256, 0, stream>>>(item_ids, basket_sizes, emb, ub);
    gemm_kernel<<<1200, 256, 0, stream>>>(ub, W_ih, b_ih, xg);
    gru_kernel<<<Bn, 512, 0, stream>>>(
        lengths, W_hh, b_hh, h0, xg, out, out + (size_t)Bn * Tn * En);
}

// Round 5
// 174.056 us; speedup vs baseline: 1.0381x; 1.0381x over previous
//
#include <hip/hip_runtime.h>
#include <stdint.h>

#define Bn 256
#define Tn 50
#define Mn 20
#define En 128
#define G3 384
#define MT 64
#define LDA 132

typedef float f32x4 __attribute__((ext_vector_type(4)));

__device__ __forceinline__ float sigmoidf(float x) {
    return 1.0f / (1.0f + __expf(-x));
}
__device__ __forceinline__ float tanh_safe(float a) {
    float ax = fabsf(a);
    float e2 = __expf(-2.0f * ax);
    return copysignf((1.0f - e2) / (1.0f + e2), a);
}

// DPP quad_perm butterfly adds over the 4-lane quad (q = tid&3).
__device__ __forceinline__ float quad_reduce_add(float x) {
    int t1 = __builtin_amdgcn_update_dpp(0, __float_as_int(x),
                                         0xB1 /*[1,0,3,2]*/, 0xF, 0xF, true);
    x += __int_as_float(t1);
    int t2 = __builtin_amdgcn_update_dpp(0, __float_as_int(x),
                                         0x4E /*[2,3,0,1]*/, 0xF, 0xF, true);
    x += __int_as_float(t2);
    return x;   // all 4 lanes of the quad hold the total
}

// ---------------------------------------------------------------------------
// Kernel 1: basket-mean gather -> ub [B*T][128]  (stored in d_out region)
// ---------------------------------------------------------------------------
__global__ __launch_bounds__(256) void gather_kernel(
    const int*   __restrict__ item_ids,
    const int*   __restrict__ basket_sizes,
    const float* __restrict__ emb,
    float* __restrict__ ub)
{
    const int bt   = blockIdx.x * 8 + (threadIdx.x >> 5);
    const int lane = threadIdx.x & 31;
    const int* ids = item_ids + (size_t)bt * Mn;
    float ax = 0.f, ay = 0.f, az = 0.f, aw = 0.f;
    #pragma unroll
    for (int m = 0; m < Mn; ++m) {
        const float4 v = *(const float4*)(emb + (size_t)ids[m] * En + lane * 4);
        ax += v.x; ay += v.y; az += v.z; aw += v.w;
    }
    const float inv = 1.0f / (float)basket_sizes[bt];
    *(float4*)(ub + (size_t)bt * En + lane * 4) =
        make_float4(ax * inv, ay * inv, az * inv, aw * inv);
}

// ---------------------------------------------------------------------------
// Kernel 2: xg = ub @ W_ih^T + b_ih.  1200 blocks (200 M x 6 N); 4x4 tile.
// ---------------------------------------------------------------------------
__global__ __launch_bounds__(256, 2) void gemm_kernel(
    const float* __restrict__ ub,
    const float* __restrict__ W_ih,
    const float* __restrict__ b_ih,
    float* __restrict__ xg)
{
    __shared__ float A[MT][LDA];
    __shared__ float Bt[64][LDA];

    const int tid  = threadIdx.x;
    const int mt   = blockIdx.x / 6;
    const int nc   = blockIdx.x % 6;
    const int row0 = mt * MT;
    const int col0 = nc * 64;

    {
        const int r = tid >> 2, seg = tid & 3;
        const float4* srcA = (const float4*)(ub + (size_t)(row0 + r) * En + seg * 32);
        const float4* srcB = (const float4*)(W_ih + (size_t)(col0 + r) * En + seg * 32);
        float4* dstA = (float4*)&A[r][seg * 32];
        float4* dstB = (float4*)&Bt[r][seg * 32];
        #pragma unroll
        for (int c = 0; c < 8; ++c) { dstA[c] = srcA[c]; dstB[c] = srcB[c]; }
    }
    __syncthreads();

    const int tx = tid & 15;
    const int ty = tid >> 4;

    float acc[4][4];
    #pragma unroll
    for (int i = 0; i < 4; ++i)
        #pragma unroll
        for (int u = 0; u < 4; ++u) acc[i][u] = 0.0f;

    #pragma unroll 4
    for (int k4 = 0; k4 < 32; ++k4) {
        const float4 av[4] = {
            *(const float4*)&A[ty +  0][k4*4], *(const float4*)&A[ty + 16][k4*4],
            *(const float4*)&A[ty + 32][k4*4], *(const float4*)&A[ty + 48][k4*4]};
        const float4 bv[4] = {
            *(const float4*)&Bt[tx +  0][k4*4], *(const float4*)&Bt[tx + 16][k4*4],
            *(const float4*)&Bt[tx + 32][k4*4], *(const float4*)&Bt[tx + 48][k4*4]};
        #pragma unroll
        for (int i = 0; i < 4; ++i)
            #pragma unroll
            for (int u = 0; u < 4; ++u) {
                acc[i][u] = fmaf(av[i].x, bv[u].x, acc[i][u]);
                acc[i][u] = fmaf(av[i].y, bv[u].y, acc[i][u]);
                acc[i][u] = fmaf(av[i].z, bv[u].z, acc[i][u]);
                acc[i][u] = fmaf(av[i].w, bv[u].w, acc[i][u]);
            }
    }

    float bias[4];
    #pragma unroll
    for (int u = 0; u < 4; ++u) bias[u] = b_ih[col0 + tx + 16*u];
    #pragma unroll
    for (int i = 0; i < 4; ++i) {
        const size_t rowoff = (size_t)(row0 + ty + 16*i) * G3;
        #pragma unroll
        for (int u = 0; u < 4; ++u)
            xg[rowoff + col0 + tx + 16*u] = acc[i][u] + bias[u];
    }
}

// ---------------------------------------------------------------------------
// Kernel 3: sequential GRU. 256 blocks x 512 threads (8 waves, 2/SIMD,
// 1 block/CU).  Thread (j in [0,128), q = tid&3) owns gate rows
// {j,128+j,256+j} of W_hh, cols [q*32,q*32+32).
//
// ROUND-5 FIX: every prior variant consumed the per-step xg load in the SAME
// iteration it was issued (the x0/x1 rotation is a physical v_mov whose
// source is the load dest -> forced s_waitcnt each step; pipeline depth 0).
// That serial ~200-600cyc L2/L3 latency per step + ~600cyc compute chain is
// the invariant ~2100 cyc/step.  Fix: stage the block's ENTIRE xg slice
// (len*384 floats <= 76.8 KB) into dynamic LDS once at kernel start; in-loop
// x-gate reads become ds_read (~120 cyc, hidden under the FMA chain).  The
// main loop now contains ZERO vmem loads.  Weights: plain loads (round-3
// best; the asm-def experiment spilled and regressed).
// ---------------------------------------------------------------------------
__global__ __launch_bounds__(512) void gru_kernel(
    const int*   __restrict__ lengths,
    const float* __restrict__ W_hh,
    const float* __restrict__ b_hh,
    const float* __restrict__ h0,
    const float* __restrict__ xg,
    float* __restrict__ out_dyn,
    float* __restrict__ out_h)
{
    extern __shared__ float smem[];
    float* hs  = smem;          // [2][En] double-buffered h
    float* sxg = smem + 2 * En; // [Tn*G3] staged x-gates (76.8 KB)

    const int tid = threadIdx.x;
    const int b   = blockIdx.x;
    const int j   = tid >> 2;        // [0,128)
    const int q   = tid & 3;         // [0,4) — the DPP quad

    const int len = lengths[b];
    const float* xgb = xg + (size_t)b * Tn * G3;
    float* outb = out_dyn + (size_t)b * Tn * En;

    // ---- one-time stage: xg[b] -> LDS (coalesced float4; only len rows) ----
    {
        const float4* src = (const float4*)xgb;
        float4* dst = (float4*)sxg;
        const int nv4 = len * (G3 / 4);      // <= 4800
        for (int i = tid; i < nv4; i += 512) dst[i] = src[i];
    }

    // Weight fragments, rotated by q at load time so compute indices are
    // compile-time constants and the 4 q-groups hit disjoint LDS bank quads.
    f32x4 w0[8], w1[8], w2[8];
    {
        const f32x4* p0 = (const f32x4*)(W_hh + (size_t)(0*En + j) * En + q * 32);
        const f32x4* p1 = (const f32x4*)(W_hh + (size_t)(1*En + j) * En + q * 32);
        const f32x4* p2 = (const f32x4*)(W_hh + (size_t)(2*En + j) * En + q * 32);
        #pragma unroll
        for (int c = 0; c < 8; ++c) {
            const int cc = (c + 2*q) & 7;
            w0[c] = p0[cc]; w1[c] = p1[cc]; w2[c] = p2[cc];
        }
    }

    const float br = b_hh[j], bz = b_hh[En + j], bn = b_hh[2*En + j];
    float hprev = h0[(size_t)b * En + j];
    if (q == 0) hs[j] = hprev;
    __syncthreads();   // full drain: staging + hs[0] visible

    int cur = 0;
    for (int t = 0; t < len; ++t) {
        // x-gates from LDS — issued first, consumed after the dots (~160cyc slack)
        const float x0r = sxg[t*G3 + j];
        const float x0z = sxg[t*G3 + En + j];
        const float x0n = sxg[t*G3 + 2*En + j];

        // partial dots over this thread's 32-col K-slice (bank-conflict-free
        // via the rotated walk)
        const f32x4* h4 = ((const f32x4*)(hs + cur * En)) + q * 8;
        float a0 = 0.f, a1 = 0.f, a2 = 0.f;
        #pragma unroll
        for (int c = 0; c < 8; ++c) {
            const f32x4 hv = h4[(c + 2*q) & 7];
            a0 = fmaf(w0[c].x, hv.x, a0); a0 = fmaf(w0[c].y, hv.y, a0);
            a0 = fmaf(w0[c].z, hv.z, a0); a0 = fmaf(w0[c].w, hv.w, a0);
            a1 = fmaf(w1[c].x, hv.x, a1); a1 = fmaf(w1[c].y, hv.y, a1);
            a1 = fmaf(w1[c].z, hv.z, a1); a1 = fmaf(w1[c].w, hv.w, a1);
            a2 = fmaf(w2[c].x, hv.x, a2); a2 = fmaf(w2[c].y, hv.y, a2);
            a2 = fmaf(w2[c].z, hv.z, a2); a2 = fmaf(w2[c].w, hv.w, a2);
        }

        // in-quad butterfly reduce over q — DPP, pure VALU
        a0 = quad_reduce_add(a0);
        a1 = quad_reduce_add(a1);
        a2 = quad_reduce_add(a2);

        // gates — computed redundantly by all 4 q-lanes
        const float r = sigmoidf(x0r + br + a0);
        const float z = sigmoidf(x0z + bz + a1);
        const float n = tanh_safe(x0n + r * (bn + a2));
        const float hnew = (1.0f - z) * n + z * hprev;

        if (q == 0) {
            hs[(cur ^ 1) * En + j] = hnew;  // write the OTHER buffer
            outb[t*En + j] = hnew;          // fire-and-forget store
        }
        // Raw barrier: drain LDS only; the outb store stays in flight.
        asm volatile("s_waitcnt lgkmcnt(0)" ::: "memory");
        __builtin_amdgcn_s_barrier();
        __builtin_amdgcn_sched_barrier(0);

        hprev = hnew;
        cur ^= 1;
    }

    if (q == 0) {
        for (int t = len; t < Tn; ++t) outb[t*En + j] = 0.0f;
        out_h[(size_t)b * En + j] = hprev;
    }
}

extern "C" void kernel_launch(void* const* d_in, const int* in_sizes, int n_in,
                              void* d_out, int out_size, void* d_ws, size_t ws_size,
                              hipStream_t stream) {
    const int*   item_ids     = (const int*)d_in[0];
    const int*   basket_sizes = (const int*)d_in[1];
    const int*   lengths      = (const int*)d_in[2];
    const float* emb          = (const float*)d_in[3];
    const float* W_ih         = (const float*)d_in[4];
    const float* W_hh         = (const float*)d_in[5];
    const float* b_ih         = (const float*)d_in[6];
    const float* b_hh         = (const float*)d_in[7];
    const float* h0           = (const float*)d_in[8];
    float* out = (float*)d_out;
    float* xg  = (float*)d_ws;   // 19.7 MB
    float* ub  = out;            // reuse out_dyn region; overwritten by gru later

    // Allow >64KB dynamic LDS for gru_kernel (HW max 160 KB on gfx950).
    // Host-side attribute set, not a stream op — safe under graph capture.
    static bool lds_attr_set = false;
    if (!lds_attr_set) {
        (void)hipFuncSetAttribute((const void*)gru_kernel,
                                  hipFuncAttributeMaxDynamicSharedMemorySize,
                                  (2 * En + Tn * G3) * (int)sizeof(float));
        lds_attr_set = true;
    }

    gather_kernel<<<(Bn * Tn) / 8, 256, 0, stream>>>(item_ids, basket_sizes, emb, ub);
    gemm_kernel<<<1200, 256, 0, stream>>>(ub, W_ih, b_ih, xg);
    gru_kernel<<<Bn, 512, (2 * En + Tn * G3) * sizeof(float), stream>>>(
        lengths, W_hh, b_hh, h0, xg, out, out + (size_t)Bn * Tn * En);
}